// Round 1
// baseline (217.530 us; speedup 1.0000x reference)
//
#include <hip/hip_runtime.h>
#include <math.h>

// DynamicHybridRouter via bf16-split MFMA (3-term: xh*wh + xh*wl + xl*wh).
// R7: R6 (grid=256, 1 block/CU, 4 waves) ran 1 wave/SIMD -> zero TLP; every
// ds_read return, vmcnt drain and per-chunk barrier idled the SIMD. Fix:
// grid=512, BM=32, 2 blocks/CU (independent barriers -> stalls overlap across
// blocks), 4 waves = (row-tile x expert-half). B staged via global_load_lds
// (LDS dest is exactly linear base+lane*16): no breg VGPRs, no ds_write, no
// vmcnt-ordering hack; VGPR fits the 2-waves/SIMD budget. CH=2 (32KB staging
// LDS -> 66KB/2 blocks). Numerics identical to R6 (same 3-term bf16 split,
// same accumulation order) so absmax stays at 0.0039.

#define NROWS 16384
#define DIM   2048
#define NEXP  64
#define BM    32
#define TPB   256
#define CH    2                  // K-steps per chunk (k-span 64)
#define NCH   (DIM / 32 / CH)    // 32 chunks
#define BUFB  16384              // bytes per staging buffer: CH*8*1024

typedef __attribute__((ext_vector_type(4))) float f32x4;
typedef __attribute__((ext_vector_type(8))) short bf16x8;

#define MFMA __builtin_amdgcn_mfma_f32_16x16x32_bf16

__device__ __forceinline__ void gl_lds16(const void* g, void* l) {
  __builtin_amdgcn_global_load_lds(
      (const __attribute__((address_space(1))) unsigned char*)g,
      (__attribute__((address_space(3))) unsigned char*)l, 16, 0, 0);
}

// ---- prologue: w [64][2048] f32 -> B-frag-ordered bf16 hi/lo in ws ----
// frag slot = (kstep*4 + t), kstep 0..63, t 0..3: 64 lanes x bf16x8.
// lane's frag: w[e=16t+(lane&15)][k = kstep*32 + (lane>>4)*8 + j], j=0..7.
__global__ void wfrag_kernel(const float* __restrict__ gw,
                             unsigned short* __restrict__ wsH,
                             unsigned short* __restrict__ wsL) {
  int slot  = blockIdx.x * 256 + threadIdx.x;   // 0..16383
  int lane  = slot & 63;
  int t     = (slot >> 6) & 3;
  int kstep = slot >> 8;
  int e  = 16 * t + (lane & 15);
  int k0 = kstep * 32 + (lane >> 4) * 8;
  const float* src = gw + (size_t)e * DIM + k0;
  bf16x8 vh, vl;
#pragma unroll
  for (int j = 0; j < 8; ++j) {
    float w = src[j];
    unsigned u = __float_as_uint(w);
    vh[j] = (short)(u >> 16);
    float hi = __uint_as_float(u & 0xffff0000u);
    float rl = w - hi;
    vl[j] = (short)(__float_as_uint(rl) >> 16);
  }
  ((bf16x8*)wsH)[slot] = vh;
  ((bf16x8*)wsL)[slot] = vl;
}

// ---- main kernel ----
__global__ __launch_bounds__(TPB, 2)
void router_mfma(const float* __restrict__ x,
                 const unsigned short* __restrict__ wsH,
                 const unsigned short* __restrict__ wsL,
                 const float* __restrict__ gb,
                 const int* __restrict__ mat,
                 float* __restrict__ out) {
  // staging: 2 buffers x CH steps x 8 units(4 expert-tiles x hi/lo) x 1KB
  // = 32KB, reused post-loop as the 32x64 logit slab (8KB).
  __shared__ __align__(16) char lds[2 * BUFB];
  __shared__ float p_a[BM], p_b[BM];
  __shared__ int   p_i[BM], p_j[BM];
  __shared__ int   s_flag;

  const int tid  = threadIdx.x;
  const int wave = tid >> 6;
  const int rt   = wave >> 1;    // row-tile 0/1: rows 16*rt .. +15
  const int eh   = wave & 1;     // expert-half: tiles {2eh, 2eh+1}
  const int lane = tid & 63;
  const int m    = lane & 15;
  const int kg   = lane >> 4;
  const int row0 = blockIdx.x * BM;

  if (tid < 64) {
    unsigned long long b = __ballot(mat[lane] == 0);
    if (lane == 0) s_flag = (b != 0ull) ? 1 : 0;
  }

  f32x4 acc[2];
  acc[0] = (f32x4)0.0f;
  acc[1] = (f32x4)0.0f;

  const unsigned char* wsHb = (const unsigned char*)wsH;
  const unsigned char* wsLb = (const unsigned char*)wsL;
  const float* xb = x + (size_t)(row0 + 16 * rt + m) * DIM + kg * 8;

  // ---- prologue: async-stage B chunk 0 (4 units/wave), load x chunk 0 ----
#pragma unroll
  for (int k = 0; k < 4; ++k) {
    const int unit = wave * 4 + k;
    const int st = unit >> 3, uu = unit & 7, t = uu >> 1, h = uu & 1;
    const size_t slot = (size_t)(st * 4 + t);
    gl_lds16((h ? wsLb : wsHb) + slot * 1024 + lane * 16, lds + unit * 1024);
  }
  float4 xA[CH][2], xB[CH][2];
#pragma unroll
  for (int st = 0; st < CH; ++st) {
    xA[st][0] = *(const float4*)(xb + st * 32);
    xA[st][1] = *(const float4*)(xb + st * 32 + 4);
  }
  __syncthreads();

  auto body = [&](int c, float4 (&cur)[CH][2], float4 (&nxt)[CH][2]) {
    const bool more = (c + 1 < NCH);
    // 1) async B-stage for chunk c+1 into the other buffer (no VGPR round-trip)
    if (more) {
      const int cn = c + 1;
      const int par2 = (cn & 1) * BUFB;
#pragma unroll
      for (int k = 0; k < 4; ++k) {
        const int unit = wave * 4 + k;
        const int st = unit >> 3, uu = unit & 7, t = uu >> 1, h = uu & 1;
        const size_t slot = (size_t)((cn * CH + st) * 4 + t);
        gl_lds16((h ? wsLb : wsHb) + slot * 1024 + lane * 16,
                 lds + par2 + unit * 1024);
      }
      // 2) x prefetch for chunk c+1 into the alternate register buffer
      const float* xp = xb + cn * (CH * 32);
#pragma unroll
      for (int st = 0; st < CH; ++st) {
        nxt[st][0] = *(const float4*)(xp + st * 32);
        nxt[st][1] = *(const float4*)(xp + st * 32 + 4);
      }
    }
    // 3) compute chunk c from buf[par] + cur
    const int par = (c & 1) * BUFB;
#pragma unroll
    for (int st = 0; st < CH; ++st) {
      const char* bb = lds + par + st * 8192 + lane * 16;
      bf16x8 bh0 = *(const bf16x8*)(bb + (4 * eh + 0) * 1024);
      bf16x8 bl0 = *(const bf16x8*)(bb + (4 * eh + 1) * 1024);
      bf16x8 bh1 = *(const bf16x8*)(bb + (4 * eh + 2) * 1024);
      bf16x8 bl1 = *(const bf16x8*)(bb + (4 * eh + 3) * 1024);
      bf16x8 ah, al;
#pragma unroll
      for (int q = 0; q < 2; ++q) {
        float4 v = cur[st][q];
        float ff[4] = {v.x, v.y, v.z, v.w};
#pragma unroll
        for (int j = 0; j < 4; ++j) {
          unsigned u = __float_as_uint(ff[j]);
          ah[q * 4 + j] = (short)(u >> 16);
          float hi = __uint_as_float(u & 0xffff0000u);
          float rl = ff[j] - hi;
          al[q * 4 + j] = (short)(__float_as_uint(rl) >> 16);
        }
      }
      acc[0] = MFMA(ah, bh0, acc[0], 0, 0, 0);
      acc[0] = MFMA(ah, bl0, acc[0], 0, 0, 0);
      acc[0] = MFMA(al, bh0, acc[0], 0, 0, 0);
      acc[1] = MFMA(ah, bh1, acc[1], 0, 0, 0);
      acc[1] = MFMA(ah, bl1, acc[1], 0, 0, 0);
      acc[1] = MFMA(al, bh1, acc[1], 0, 0, 0);
    }
    // 4) one barrier per chunk (drains the async B-stage + x loads)
    __syncthreads();
  };

#pragma unroll 1
  for (int c = 0; c < NCH; c += 2) {
    body(c, xA, xB);
    body(c + 1, xB, xA);
  }

  // ---- epilogue: slab reuse (all compute done after final barrier) ----
  // C/D layout: col(lane&15)=expert-in-tile, row=kg*4+reg -> local x-row.
  float* slab = (float*)lds;   // [32 rows][64 experts]
  {
    float gbv0 = gb[eh * 32 + m];
    float gbv1 = gb[eh * 32 + 16 + m];
#pragma unroll
    for (int reg = 0; reg < 4; ++reg) {
      slab[(16 * rt + kg * 4 + reg) * NEXP + eh * 32 + m]      = acc[0][reg] + gbv0;
      slab[(16 * rt + kg * 4 + reg) * NEXP + eh * 32 + 16 + m] = acc[1][reg] + gbv1;
    }
  }
  __syncthreads();

  const int flag = s_flag;

  // per-row routing (threads 0..31; rotated scan spreads LDS banks)
  if (tid < BM) {
    const float* rowp = slab + tid * NEXP;
    if (flag == 0) {
      float m1 = -1e30f, m2 = -1e30f;
      int i1 = 0, i2 = 0;
      for (int ee = 0; ee < NEXP; ++ee) {
        int e = (ee + tid) & (NEXP - 1);
        float v = rowp[e];
        if (v > m1) { m2 = m1; i2 = i1; m1 = v; i1 = e; }
        else if (v > m2) { m2 = v; i2 = e; }
      }
      float t = expf(m2 - m1);
      float pa = 1.0f / (1.0f + t);
      p_a[tid] = pa;
      p_b[tid] = t * pa;
      p_i[tid] = i1;
      p_j[tid] = i2;
    } else {
      float mx = -1e30f;
      for (int ee = 0; ee < NEXP; ++ee)
        mx = fmaxf(mx, rowp[(ee + tid) & (NEXP - 1)]);
      float ssum = 0.0f;
      for (int ee = 0; ee < NEXP; ++ee)
        ssum += expf((rowp[(ee + tid) & (NEXP - 1)] - mx) * 0.5f);  // /T=2
      p_a[tid] = mx;
      p_b[tid] = 1.0f / ssum;
    }
  }
  __syncthreads();

  // output: 32x64 tile = 512 float4, 2 per thread
#pragma unroll
  for (int i = 0; i < 2; ++i) {
    int q  = tid + i * TPB;
    int r  = q >> 4;
    int e0 = (q & 15) * 4;
    float4 v;
    if (flag == 0) {
      int i1 = p_i[r], i2 = p_j[r];
      float a = p_a[r], b = p_b[r];
      v.x = (e0 + 0 == i1) ? a : (e0 + 0 == i2) ? b : 0.0f;
      v.y = (e0 + 1 == i1) ? a : (e0 + 1 == i2) ? b : 0.0f;
      v.z = (e0 + 2 == i1) ? a : (e0 + 2 == i2) ? b : 0.0f;
      v.w = (e0 + 3 == i1) ? a : (e0 + 3 == i2) ? b : 0.0f;
    } else {
      float mx = p_a[r], inv = p_b[r];
      const float* rowp = slab + r * NEXP + e0;
      v.x = expf((rowp[0] - mx) * 0.5f) * inv;
      v.y = expf((rowp[1] - mx) * 0.5f) * inv;
      v.z = expf((rowp[2] - mx) * 0.5f) * inv;
      v.w = expf((rowp[3] - mx) * 0.5f) * inv;
    }
    *(float4*)(out + (size_t)(row0 + r) * NEXP + e0) = v;
  }
}

extern "C" void kernel_launch(void* const* d_in, const int* in_sizes, int n_in,
                              void* d_out, int out_size, void* d_ws, size_t ws_size,
                              hipStream_t stream) {
  const float* x  = (const float*)d_in[0];
  const float* gw = (const float*)d_in[1];
  const float* gb = (const float*)d_in[2];
  const int*   mt = (const int*)d_in[3];
  float* outp = (float*)d_out;
  (void)in_sizes; (void)n_in; (void)out_size; (void)ws_size;

  unsigned short* wsH = (unsigned short*)d_ws;
  unsigned short* wsL = wsH + 64 * DIM;

  wfrag_kernel<<<64, 256, 0, stream>>>(gw, wsH, wsL);
  router_mfma<<<NROWS / BM, TPB, 0, stream>>>(x, wsH, wsL, gb, mt, outp);
}

// Round 2
// 212.083 us; speedup vs baseline: 1.0257x; 1.0257x over previous
//
#include <hip/hip_runtime.h>
#include <math.h>

// DynamicHybridRouter via bf16-split MFMA (3-term: xh*wh + xh*wl + xl*wh).
// R8: R7 (BM=32, 2 blocks/CU) regressed 207->218: halving work-per-barrier
// (32 barriers, 12 MFMA/chunk) + doubling B L2 traffic ate the TLP gain.
// Revert to R6 geometry (BM=64, grid=256, CH=4, 16 chunks, 48 MFMA/chunk).
// Remaining stall in R6 was __syncthreads' forced vmcnt(0): it drained the
// x(c+1) prefetch every chunk. Fix = T3/T4 counted-vmcnt pipeline:
//  - B staged via global_load_lds (no breg VGPRs, no ds_write commit),
//  - per chunk: issue 8 gl_lds(B,c+1) then 8 x-dwordx4(c+1) [order pinned
//    with sched_barrier], compute chunk c, s_waitcnt vmcnt(8) (drains only
//    the B loads; x rides across the barrier), raw s_barrier.
// Each wave drains its own gl_lds before the rendezvous -> buffer c+1 safe
// to read after barrier; buffer being written was last read 2 barriers ago.
// Numerics identical to R6 (same 3-term split, same accumulation order).

#define NROWS 16384
#define DIM   2048
#define NEXP  64
#define BM    64
#define TPB   256
#define CH    4                  // K-steps per chunk (k-span 128)
#define NCH   (DIM / 32 / CH)    // 16 chunks
#define BUFB  32768              // bytes per staging buffer: CH*8*1024

typedef __attribute__((ext_vector_type(4))) float f32x4;
typedef __attribute__((ext_vector_type(8))) short bf16x8;

#define MFMA __builtin_amdgcn_mfma_f32_16x16x32_bf16

__device__ __forceinline__ void gl_lds16(const void* g, void* l) {
  __builtin_amdgcn_global_load_lds(
      (const __attribute__((address_space(1))) unsigned char*)g,
      (__attribute__((address_space(3))) unsigned char*)l, 16, 0, 0);
}

// ---- prologue: w [64][2048] f32 -> B-frag-ordered bf16 hi/lo in ws ----
// frag slot = (kstep*4 + t), kstep 0..63, t 0..3: 64 lanes x bf16x8.
// lane's frag: w[e=16t+(lane&15)][k = kstep*32 + (lane>>4)*8 + j], j=0..7.
__global__ void wfrag_kernel(const float* __restrict__ gw,
                             unsigned short* __restrict__ wsH,
                             unsigned short* __restrict__ wsL) {
  int slot  = blockIdx.x * 256 + threadIdx.x;   // 0..16383
  int lane  = slot & 63;
  int t     = (slot >> 6) & 3;
  int kstep = slot >> 8;
  int e  = 16 * t + (lane & 15);
  int k0 = kstep * 32 + (lane >> 4) * 8;
  const float* src = gw + (size_t)e * DIM + k0;
  bf16x8 vh, vl;
#pragma unroll
  for (int j = 0; j < 8; ++j) {
    float w = src[j];
    unsigned u = __float_as_uint(w);
    vh[j] = (short)(u >> 16);
    float hi = __uint_as_float(u & 0xffff0000u);
    float rl = w - hi;
    vl[j] = (short)(__float_as_uint(rl) >> 16);
  }
  ((bf16x8*)wsH)[slot] = vh;
  ((bf16x8*)wsL)[slot] = vl;
}

// ---- main kernel ----
__global__ __launch_bounds__(TPB, 1)
void router_mfma(const float* __restrict__ x,
                 const unsigned short* __restrict__ wsH,
                 const unsigned short* __restrict__ wsL,
                 const float* __restrict__ gb,
                 const int* __restrict__ mat,
                 float* __restrict__ out) {
  // staging: 2 buffers x CH steps x 8 units(4 tiles x hi/lo) x 1KB = 64KB,
  // reused post-loop as the 64x64 logit slab (16KB, inside buf0; last chunk
  // (c=15, odd) computes from buf1 -> no overlap with slab writes).
  __shared__ __align__(16) char lds[2 * BUFB];
  __shared__ float p_a[BM], p_b[BM];
  __shared__ int   p_i[BM], p_j[BM];
  __shared__ int   s_flag;

  const int tid  = threadIdx.x;
  const int wave = tid >> 6;     // row group: rows 16*wave .. +15; stages step st=wave
  const int lane = tid & 63;
  const int m    = lane & 15;
  const int kg   = lane >> 4;
  const int row0 = blockIdx.x * BM;

  if (tid < 64) {
    unsigned long long b = __ballot(mat[lane] == 0);
    if (lane == 0) s_flag = (b != 0ull) ? 1 : 0;
  }

  f32x4 acc[4];
#pragma unroll
  for (int t = 0; t < 4; ++t) acc[t] = (f32x4)0.0f;

  const unsigned char* wsHb = (const unsigned char*)wsH;
  const unsigned char* wsLb = (const unsigned char*)wsL;
  const float* xb = x + (size_t)(row0 + 16 * wave + m) * DIM + kg * 8;

  // wave w stages step st=w of chunk c: 8 units (4 tiles x hi/lo), 1KB each.
  auto stageB = [&](int c) {
    const int par = (c & 1) * BUFB;
#pragma unroll
    for (int u = 0; u < 8; ++u) {
      int t = u >> 1, h = u & 1;
      size_t slot = (size_t)((c * CH + wave) * 4 + t);
      gl_lds16((h ? wsLb : wsHb) + slot * 1024 + (size_t)lane * 16,
               lds + par + (wave * 8 + u) * 1024);
    }
  };
  auto loadX = [&](int c, float4 (&dst)[CH][2]) {
    const float* xp = xb + c * (CH * 32);
#pragma unroll
    for (int st = 0; st < CH; ++st) {
      dst[st][0] = *(const float4*)(xp + st * 32);
      dst[st][1] = *(const float4*)(xp + st * 32 + 4);
    }
  };
  auto computeC = [&](int c, float4 (&cur)[CH][2]) {
    const int par = (c & 1) * BUFB;
#pragma unroll
    for (int st = 0; st < CH; ++st) {
      const char* bb = lds + par + st * 8192 + lane * 16;
      bf16x8 bh[4], bl[4];
#pragma unroll
      for (int t = 0; t < 4; ++t) {
        bh[t] = *(const bf16x8*)(bb + (2 * t) * 1024);
        bl[t] = *(const bf16x8*)(bb + (2 * t + 1) * 1024);
      }
      bf16x8 ah, al;
#pragma unroll
      for (int q = 0; q < 2; ++q) {
        float4 v = cur[st][q];
        float ff[4] = {v.x, v.y, v.z, v.w};
#pragma unroll
        for (int j = 0; j < 4; ++j) {
          unsigned u = __float_as_uint(ff[j]);
          ah[q * 4 + j] = (short)(u >> 16);
          float hi = __uint_as_float(u & 0xffff0000u);
          float rl = ff[j] - hi;
          al[q * 4 + j] = (short)(__float_as_uint(rl) >> 16);
        }
      }
#pragma unroll
      for (int t = 0; t < 4; ++t) {
        acc[t] = MFMA(ah, bh[t], acc[t], 0, 0, 0);
        acc[t] = MFMA(ah, bl[t], acc[t], 0, 0, 0);
        acc[t] = MFMA(al, bh[t], acc[t], 0, 0, 0);
      }
    }
  };

  float4 xA[CH][2], xB[CH][2];

  // ---- prologue: stage chunk 0, drain B, barrier ----
  stageB(0);
  __builtin_amdgcn_sched_barrier(0);
  loadX(0, xA);
  __builtin_amdgcn_sched_barrier(0);
  asm volatile("s_waitcnt vmcnt(8)" ::: "memory");   // B(0) in LDS; x(0) in flight
  __builtin_amdgcn_sched_barrier(0);
  __builtin_amdgcn_s_barrier();
  __builtin_amdgcn_sched_barrier(0);

  auto body = [&](int c, float4 (&cur)[CH][2], float4 (&nxt)[CH][2]) {
    const bool more = (c + 1 < NCH);
    if (more) {
      stageB(c + 1);                       // 8 gl_lds (oldest outstanding)
      __builtin_amdgcn_sched_barrier(0);
      loadX(c + 1, nxt);                   // 8 x dwordx4 (youngest)
      __builtin_amdgcn_sched_barrier(0);
    }
    computeC(c, cur);                      // no VMEM ops inside
    if (more) {
      // drain only the 8 B gl_lds; the 8 x loads ride across the barrier
      asm volatile("s_waitcnt vmcnt(8)" ::: "memory");
    }
    __builtin_amdgcn_sched_barrier(0);
    __builtin_amdgcn_s_barrier();
    __builtin_amdgcn_sched_barrier(0);
  };

#pragma unroll 1
  for (int c = 0; c < NCH; c += 2) {
    body(c, xA, xB);
    body(c + 1, xB, xA);
  }

  // ---- epilogue: slab reuse (all compute done after final barrier) ----
  // C/D layout: col(lane&15)=expert-in-tile, row=kg*4+reg -> local x-row.
  float* slab = (float*)lds;   // [64 rows][64 experts]
  {
    float gbv[4];
#pragma unroll
    for (int t = 0; t < 4; ++t) gbv[t] = gb[16 * t + m];
#pragma unroll
    for (int t = 0; t < 4; ++t)
#pragma unroll
      for (int reg = 0; reg < 4; ++reg)
        slab[(16 * wave + kg * 4 + reg) * NEXP + 16 * t + m] = acc[t][reg] + gbv[t];
  }
  __syncthreads();

  const int flag = s_flag;

  // per-row routing (threads 0..63; rotated scan spreads LDS banks)
  if (tid < BM) {
    const float* rowp = slab + tid * NEXP;
    if (flag == 0) {
      float m1 = -1e30f, m2 = -1e30f;
      int i1 = 0, i2 = 0;
      for (int ee = 0; ee < NEXP; ++ee) {
        int e = (ee + tid) & (NEXP - 1);
        float v = rowp[e];
        if (v > m1) { m2 = m1; i2 = i1; m1 = v; i1 = e; }
        else if (v > m2) { m2 = v; i2 = e; }
      }
      float t = expf(m2 - m1);
      float pa = 1.0f / (1.0f + t);
      p_a[tid] = pa;
      p_b[tid] = t * pa;
      p_i[tid] = i1;
      p_j[tid] = i2;
    } else {
      float mx = -1e30f;
      for (int ee = 0; ee < NEXP; ++ee)
        mx = fmaxf(mx, rowp[(ee + tid) & (NEXP - 1)]);
      float ssum = 0.0f;
      for (int ee = 0; ee < NEXP; ++ee)
        ssum += expf((rowp[(ee + tid) & (NEXP - 1)] - mx) * 0.5f);  // /T=2
      p_a[tid] = mx;
      p_b[tid] = 1.0f / ssum;
    }
  }
  __syncthreads();

  // output: 64x64 tile = 1024 float4, 4 per thread
#pragma unroll
  for (int i = 0; i < 4; ++i) {
    int q  = tid + i * TPB;
    int r  = q >> 4;
    int e0 = (q & 15) * 4;
    float4 v;
    if (flag == 0) {
      int i1 = p_i[r], i2 = p_j[r];
      float a = p_a[r], b = p_b[r];
      v.x = (e0 + 0 == i1) ? a : (e0 + 0 == i2) ? b : 0.0f;
      v.y = (e0 + 1 == i1) ? a : (e0 + 1 == i2) ? b : 0.0f;
      v.z = (e0 + 2 == i1) ? a : (e0 + 2 == i2) ? b : 0.0f;
      v.w = (e0 + 3 == i1) ? a : (e0 + 3 == i2) ? b : 0.0f;
    } else {
      float mx = p_a[r], inv = p_b[r];
      const float* rowp = slab + r * NEXP + e0;
      v.x = expf((rowp[0] - mx) * 0.5f) * inv;
      v.y = expf((rowp[1] - mx) * 0.5f) * inv;
      v.z = expf((rowp[2] - mx) * 0.5f) * inv;
      v.w = expf((rowp[3] - mx) * 0.5f) * inv;
    }
    *(float4*)(out + (size_t)(row0 + r) * NEXP + e0) = v;
  }
}

extern "C" void kernel_launch(void* const* d_in, const int* in_sizes, int n_in,
                              void* d_out, int out_size, void* d_ws, size_t ws_size,
                              hipStream_t stream) {
  const float* x  = (const float*)d_in[0];
  const float* gw = (const float*)d_in[1];
  const float* gb = (const float*)d_in[2];
  const int*   mt = (const int*)d_in[3];
  float* outp = (float*)d_out;
  (void)in_sizes; (void)n_in; (void)out_size; (void)ws_size;

  unsigned short* wsH = (unsigned short*)d_ws;
  unsigned short* wsL = wsH + 64 * DIM;

  wfrag_kernel<<<64, 256, 0, stream>>>(gw, wsH, wsL);
  router_mfma<<<NROWS / BM, TPB, 0, stream>>>(x, wsH, wsL, gb, mt, outp);
}